// Round 1
// baseline (385.839 us; speedup 1.0000x reference)
//
#include <hip/hip_runtime.h>
#include <hip/hip_bf16.h>

// Sizes
#define NBATCH 128   // conv channels (o dim)
#define NSLIDE 256   // s dim
#define PART_ELEMS 32768          // 256 s x 128 o per partial unit
#define NPART 424                 // h1:18*8 + h2:10*16 + h3:5*24
// partial bf16: 424 * 32768 * 2 B = 27.75 MB (< 34.6 MB proven ws)

using ushort4v = __attribute__((ext_vector_type(4))) unsigned short;
using bf16x8   = __attribute__((ext_vector_type(8))) __bf16;
using floatx4  = __attribute__((ext_vector_type(4))) float;

__device__ __forceinline__ unsigned short f2bf(float f) {
  union { float f; unsigned u; } v; v.f = f;
  unsigned r = v.u + 0x7fffu + ((v.u >> 16) & 1u);  // RNE (inputs finite)
  return (unsigned short)(r >> 16);
}

// v_cvt_pk_bf16_f32: dst = {bf16(src0) lo16, bf16(src1) hi16}, HW RNE.
__device__ __forceinline__ ushort4v pack4(const float4& a) {
  unsigned lo, hi;
  asm("v_cvt_pk_bf16_f32 %0, %1, %2" : "=v"(lo) : "v"(a.x), "v"(a.y));
  asm("v_cvt_pk_bf16_f32 %0, %1, %2" : "=v"(hi) : "v"(a.z), "v"(a.w));
  union { unsigned u[2]; ushort4v v; } r;
  r.u[0] = lo; r.u[1] = hi;
  return r.v;
}

// 848 wgs. XCD-aware decomposition: hardware round-robins wg -> XCD (bx % 8),
// and ch in [0,8) partitions BOTH W (c-columns) and Ec (channel columns) into
// disjoint sets. So we pin ch = bx & 7: every XCD touches only its own 1/8 of
// W and Ec, W-chunk sharers (same k, across p/m) and A-tile sharers (same
// (ch,p,m), across k) are co-resident on one XCD -> L2 captures the reuse.
// Per ch: h1 6k*3p*2m=36, h2 5k*2a*2p*2m=40, h3 5k*3a*2m=30 -> 106 = 848/8.
__global__ __launch_bounds__(256, 3) void gemm_uniform(
    const float* __restrict__ Ec,
    const float* __restrict__ W1, const float* __restrict__ W2,
    const float* __restrict__ W3,
    unsigned short* __restrict__ part)
{
  const int bx = blockIdx.x;
  const int ch = bx & 7;          // == XCD id under round-robin dispatch
  const int i  = bx >> 3;         // 0..105 within this XCD
  int htype, k, a, p, m;
  if (i < 36) {                   // h1: 6 k-groups of 6 members (p,m)
    htype = 0; k = i / 6; int mem = i - k * 6;
    a = 0; p = mem >> 1; m = mem & 1;
  } else if (i < 76) {            // h2: 10 (k,a)-groups of 4 members (p,m)
    htype = 1; int t = i - 36; int g = t >> 2, mem = t & 3;
    k = g >> 1; a = g & 1; p = mem >> 1; m = mem & 1;
  } else {                        // h3: 15 (k,a)-groups of 2 members (m)
    htype = 2; int t = i - 76; int g = t >> 1;
    k = g / 3; a = g - k * 3; p = 0; m = t & 1;
  }
  const int l = p + a;                  // Ec height index
  const int h = htype + 1;
  const float* wbase = (htype == 0) ? W1 : ((htype == 1) ? W2 : W3);
  const long o_stride = 16384L * h;     // W element stride over o
  const long c_stride = 128L * h;       // W element stride over c

  // partial unit index (one owner per (slot, a, ch); m-halves write disjoint rows)
  int slot, seq;
  if (htype == 0)      { slot = 3 * k + p;      seq = ch; }
  else if (htype == 1) { slot = 18 + 2 * k + p; seq = a * 8 + ch; }
  else                 { slot = 28 + k;         seq = a * 8 + ch; }
  int pbase;
  if (slot < 18)      pbase = slot * 8;
  else if (slot < 28) pbase = 144 + (slot - 18) * 16;
  else                pbase = 304 + (slot - 28) * 24;
  const int pslot = pbase + seq;

  // LDS: bf16 tiles 128 rows x 64 k, XOR-swizzled in 16 B granules (verified r3).
  __shared__ __align__(16) unsigned short As[128 * 64];
  __shared__ __align__(16) unsigned short Bs[128 * 64];

  const int tid = threadIdx.x;
  const int c16 = tid & 15;            // 16 lanes x 16 B = 256 B dense per row
  const int r0  = tid >> 4;            // rows r0 + 16q
  // LDS store offset pieces: granule gh = c16>>1, half = c16&1
  const int gh   = c16 >> 1;
  const int half4 = (c16 & 1) * 4;     // short offset within granule

  const float* aP = Ec + (long)l * 128 + (long)(m * 128 + r0) * 384 + c16 * 4;
  const float* wP = wbase + (long)k * 128 * o_stride + (long)a * 128
                    + (long)r0 * o_stride + c16 * 4;

  const int wave = tid >> 6;
  const int lane = tid & 63;
  const int wm = (wave >> 1) * 64;
  const int wn = (wave & 1) * 64;
  const int lr = lane & 15;
  const int lq = lane >> 4;

  floatx4 acc[4][4];
#pragma unroll
  for (int i2 = 0; i2 < 4; ++i2)
#pragma unroll
    for (int j = 0; j < 4; ++j) acc[i2][j] = (floatx4){0.f, 0.f, 0.f, 0.f};

  float4 aL[8], wL[8];

  // iteration t in [0,32): c = ch*16 + (t>>1), d-half = t&1
#define LOAD_TILE(t_)                                                           \
  {                                                                             \
    const int tv = (t_);                                                        \
    const long cA = (long)(ch * 16 + (tv >> 1)) * 98304 + (long)(tv & 1) * 64;  \
    const long cB = (long)(ch * 16 + (tv >> 1)) * c_stride + (long)(tv & 1) * 64;\
    _Pragma("unroll")                                                           \
    for (int q = 0; q < 8; ++q) {                                               \
      aL[q] = *reinterpret_cast<const float4*>(aP + cA + (long)q * (16 * 384)); \
      wL[q] = *reinterpret_cast<const float4*>(wP + cB + (long)q * 16 * o_stride);\
    }                                                                           \
  }

  LOAD_TILE(0);

  for (int t = 0; t < 32; ++t) {
    // convert + swizzled LDS store: row = r0+16q; granule g' = gh ^ (row&7)
#pragma unroll
    for (int q = 0; q < 8; ++q) {
      const int row = r0 + 16 * q;
      const int off = row * 64 + ((gh ^ (row & 7)) << 3) + half4;
      *reinterpret_cast<ushort4v*>(&As[off]) = pack4(aL[q]);
      *reinterpret_cast<ushort4v*>(&Bs[off]) = pack4(wL[q]);
    }
    // prefetch issued BEFORE the barrier: aL/wL are dead after the packs, and
    // issuing here widens the latency window by barrier + other waves' stores.
    if (t + 1 < 32) LOAD_TILE(t + 1);
    __syncthreads();

#pragma unroll
    for (int ks = 0; ks < 2; ++ks) {
      bf16x8 af[4], bf_[4];
#pragma unroll
      for (int i2 = 0; i2 < 4; ++i2) {
        const int row = wm + 16 * i2 + lr;
        const int col = (((ks * 4 + lq) ^ (row & 7)) << 3);
        af[i2] = *reinterpret_cast<const bf16x8*>(&As[row * 64 + col]);
      }
#pragma unroll
      for (int j = 0; j < 4; ++j) {
        const int row = wn + 16 * j + lr;
        const int col = (((ks * 4 + lq) ^ (row & 7)) << 3);
        bf_[j] = *reinterpret_cast<const bf16x8*>(&Bs[row * 64 + col]);
      }
#pragma unroll
      for (int i2 = 0; i2 < 4; ++i2)
#pragma unroll
        for (int j = 0; j < 4; ++j)
          acc[i2][j] = __builtin_amdgcn_mfma_f32_16x16x32_bf16(af[i2], bf_[j], acc[i2][j], 0, 0, 0);
    }
    __syncthreads();
  }
#undef LOAD_TILE

  // bf16 partial store (D layout: row = lq*4+r, col = lr); m-half picks row block
  unsigned short* base = part + (long)pslot * PART_ELEMS + (long)m * 128 * NBATCH;
#pragma unroll
  for (int i2 = 0; i2 < 4; ++i2) {
#pragma unroll
    for (int j = 0; j < 4; ++j) {
#pragma unroll
      for (int r = 0; r < 4; ++r) {
        int s = wm + 16 * i2 + lq * 4 + r;
        int o = wn + 16 * j + lr;
        base[s * NBATCH + o] = f2bf(acc[i2][j][r]);
      }
    }
  }
}

__device__ __forceinline__ float bf2f(unsigned short u) {
  union { unsigned u; float f; } v; v.u = ((unsigned)u) << 16; return v.f;
}

__global__ void epilogue(const unsigned short* __restrict__ part,
                         const float* __restrict__ b1, const float* __restrict__ b2,
                         const float* __restrict__ b3, float* __restrict__ out)
{
  int t = blockIdx.x * 256 + threadIdx.x;   // 32768 threads: (s,o)
  int o = t & 127;
  int s = t >> 7;
  const long idx = (long)s * NBATCH + o;

  float v[33];
#pragma unroll
  for (int sl = 0; sl < 18; ++sl) {          // h1: 8 partials each
    float a = 0.f;
#pragma unroll
    for (int c = 0; c < 8; ++c) a += bf2f(part[(long)(sl * 8 + c) * PART_ELEMS + idx]);
    v[sl] = a;
  }
#pragma unroll
  for (int sl = 0; sl < 10; ++sl) {          // h2: 16 partials each
    float a = 0.f;
#pragma unroll
    for (int c = 0; c < 16; ++c) a += bf2f(part[(long)(144 + sl * 16 + c) * PART_ELEMS + idx]);
    v[18 + sl] = a;
  }
#pragma unroll
  for (int sl = 0; sl < 5; ++sl) {           // h3: 24 partials each
    float a = 0.f;
#pragma unroll
    for (int c = 0; c < 24; ++c) a += bf2f(part[(long)(304 + sl * 24 + c) * PART_ELEMS + idx]);
    v[28 + sl] = a;
  }

  float r[16];
#pragma unroll
  for (int k = 0; k < 6; ++k) {   // h=1, kernels 3k
    float mx = fmaxf(fmaxf(v[3 * k + 0], v[3 * k + 1]), v[3 * k + 2]);
    r[3 * k + 0] = fmaxf(mx + b1[k * 128 + o], 0.f);
  }
#pragma unroll
  for (int k = 0; k < 5; ++k) {   // h=2, kernels 3k+1
    float mx = fmaxf(v[18 + 2 * k], v[18 + 2 * k + 1]);
    r[3 * k + 1] = fmaxf(mx + b2[k * 128 + o], 0.f);
  }
#pragma unroll
  for (int k = 0; k < 5; ++k) {   // h=3, kernels 3k+2
    r[3 * k + 2] = fmaxf(v[28 + k] + b3[k * 128 + o], 0.f);
  }
  float* op = out + ((long)o * 256 + s) * 16;   // out[B][S][1][K]
  reinterpret_cast<float4*>(op)[0] = make_float4(r[0], r[1], r[2], r[3]);
  reinterpret_cast<float4*>(op)[1] = make_float4(r[4], r[5], r[6], r[7]);
  reinterpret_cast<float4*>(op)[2] = make_float4(r[8], r[9], r[10], r[11]);
  reinterpret_cast<float4*>(op)[3] = make_float4(r[12], r[13], r[14], r[15]);
}

extern "C" void kernel_launch(void* const* d_in, const int* in_sizes, int n_in,
                              void* d_out, int out_size, void* d_ws, size_t ws_size,
                              hipStream_t stream) {
  const float* Ec = (const float*)d_in[0];
  const float* W1 = (const float*)d_in[1];
  const float* W2 = (const float*)d_in[2];
  const float* W3 = (const float*)d_in[3];
  const float* b1 = (const float*)d_in[4];
  const float* b2 = (const float*)d_in[5];
  const float* b3 = (const float*)d_in[6];
  float* out = (float*)d_out;
  unsigned short* part = (unsigned short*)d_ws;   // 27.75 MB bf16, fully overwritten

  gemm_uniform<<<848, 256, 0, stream>>>(Ec, W1, W2, W3, part);
  epilogue<<<(NSLIDE * NBATCH) / 256, 256, 0, stream>>>(part, b1, b2, b3, out);
}

// Round 2
// 376.023 us; speedup vs baseline: 1.0261x; 1.0261x over previous
//
#include <hip/hip_runtime.h>
#include <hip/hip_bf16.h>

// Sizes
#define NBATCH 128   // conv channels (o dim)
#define NSLIDE 256   // s dim
#define PART_ELEMS 32768          // 256 s x 128 o per partial unit
#define NPART 424                 // h1:18*8 + h2:10*16 + h3:5*24
// ws: partial bf16 424*32768*2 = 27.79 MB, + sums fp32 33*32768*4 = 4.33 MB
//     total 32.1 MB < 34.6 MB proven ws
#define SUMS_OFF_SHORTS (NPART * PART_ELEMS)   // sums start (aligned: 27787264 % 16 == 0)

using ushort4v = __attribute__((ext_vector_type(4))) unsigned short;
using ushort8v = __attribute__((ext_vector_type(8))) unsigned short;
using bf16x8   = __attribute__((ext_vector_type(8))) __bf16;
using floatx4  = __attribute__((ext_vector_type(4))) float;

__device__ __forceinline__ unsigned short f2bf(float f) {
  union { float f; unsigned u; } v; v.f = f;
  unsigned r = v.u + 0x7fffu + ((v.u >> 16) & 1u);  // RNE (inputs finite)
  return (unsigned short)(r >> 16);
}

// v_cvt_pk_bf16_f32: dst = {bf16(src0) lo16, bf16(src1) hi16}, HW RNE.
__device__ __forceinline__ ushort4v pack4(const float4& a) {
  unsigned lo, hi;
  asm("v_cvt_pk_bf16_f32 %0, %1, %2" : "=v"(lo) : "v"(a.x), "v"(a.y));
  asm("v_cvt_pk_bf16_f32 %0, %1, %2" : "=v"(hi) : "v"(a.z), "v"(a.w));
  union { unsigned u[2]; ushort4v v; } r;
  r.u[0] = lo; r.u[1] = hi;
  return r.v;
}

__device__ __forceinline__ float bf2f(unsigned short u) {
  union { unsigned u; float f; } v; v.u = ((unsigned)u) << 16; return v.f;
}

// 848 wgs. XCD-aware decomposition (r1-verified: FETCH dropped to ~unique bytes):
// ch = bx & 7 == XCD id under round-robin dispatch; ch partitions both W
// (c-columns) and Ec into disjoint 1/8ths -> all reuse is XCD-local in L2.
// Per ch: h1 36 + h2 40 + h3 30 = 106 = 848/8.
//
// r2 change: double-buffered LDS (2x32KB), ONE barrier per K-step.
// MFMA(t) on buf[cur] overlaps pack/store(t+1) into buf[cur^1] and the issue
// of global loads(t+2). Removes the 2-barrier drain that left MfmaUtil at 13%.
// LDS 64KB -> 2 blocks/CU == measured occupancy of the old version, so the
// cap costs nothing.
__global__ __launch_bounds__(256, 2) void gemm_uniform(
    const float* __restrict__ Ec,
    const float* __restrict__ W1, const float* __restrict__ W2,
    const float* __restrict__ W3,
    unsigned short* __restrict__ part)
{
  const int bx = blockIdx.x;
  const int ch = bx & 7;          // == XCD id under round-robin dispatch
  const int i  = bx >> 3;         // 0..105 within this XCD
  int htype, k, a, p, m;
  if (i < 36) {                   // h1: 6 k-groups of 6 members (p,m)
    htype = 0; k = i / 6; int mem = i - k * 6;
    a = 0; p = mem >> 1; m = mem & 1;
  } else if (i < 76) {            // h2: 10 (k,a)-groups of 4 members (p,m)
    htype = 1; int t = i - 36; int g = t >> 2, mem = t & 3;
    k = g >> 1; a = g & 1; p = mem >> 1; m = mem & 1;
  } else {                        // h3: 15 (k,a)-groups of 2 members (m)
    htype = 2; int t = i - 76; int g = t >> 1;
    k = g / 3; a = g - k * 3; p = 0; m = t & 1;
  }
  const int l = p + a;                  // Ec height index
  const int h = htype + 1;
  const float* wbase = (htype == 0) ? W1 : ((htype == 1) ? W2 : W3);
  const long o_stride = 16384L * h;     // W element stride over o
  const long c_stride = 128L * h;       // W element stride over c

  // partial unit index (one owner per (slot, a, ch); m-halves write disjoint rows)
  int slot, seq;
  if (htype == 0)      { slot = 3 * k + p;      seq = ch; }
  else if (htype == 1) { slot = 18 + 2 * k + p; seq = a * 8 + ch; }
  else                 { slot = 28 + k;         seq = a * 8 + ch; }
  int pbase;
  if (slot < 18)      pbase = slot * 8;
  else if (slot < 28) pbase = 144 + (slot - 18) * 16;
  else                pbase = 304 + (slot - 28) * 24;
  const int pslot = pbase + seq;

  // LDS: double-buffered bf16 tiles 128 rows x 64 k, XOR-swizzled in 16 B granules.
  __shared__ __align__(16) unsigned short As[2][128 * 64];
  __shared__ __align__(16) unsigned short Bs[2][128 * 64];

  const int tid = threadIdx.x;
  const int c16 = tid & 15;            // 16 lanes x 16 B = 256 B dense per row
  const int r0  = tid >> 4;            // rows r0 + 16q
  // LDS store offset pieces: granule gh = c16>>1, half = c16&1
  const int gh   = c16 >> 1;
  const int half4 = (c16 & 1) * 4;     // short offset within granule

  const float* aP = Ec + (long)l * 128 + (long)(m * 128 + r0) * 384 + c16 * 4;
  const float* wP = wbase + (long)k * 128 * o_stride + (long)a * 128
                    + (long)r0 * o_stride + c16 * 4;

  const int wave = tid >> 6;
  const int lane = tid & 63;
  const int wm = (wave >> 1) * 64;
  const int wn = (wave & 1) * 64;
  const int lr = lane & 15;
  const int lq = lane >> 4;

  floatx4 acc[4][4];
#pragma unroll
  for (int i2 = 0; i2 < 4; ++i2)
#pragma unroll
    for (int j = 0; j < 4; ++j) acc[i2][j] = (floatx4){0.f, 0.f, 0.f, 0.f};

  float4 aL[8], wL[8];

  // iteration t in [0,32): c = ch*16 + (t>>1), d-half = t&1
#define LOAD_TILE(t_)                                                           \
  {                                                                             \
    const int tv = (t_);                                                        \
    const long cA = (long)(ch * 16 + (tv >> 1)) * 98304 + (long)(tv & 1) * 64;  \
    const long cB = (long)(ch * 16 + (tv >> 1)) * c_stride + (long)(tv & 1) * 64;\
    _Pragma("unroll")                                                           \
    for (int q = 0; q < 8; ++q) {                                               \
      aL[q] = *reinterpret_cast<const float4*>(aP + cA + (long)q * (16 * 384)); \
      wL[q] = *reinterpret_cast<const float4*>(wP + cB + (long)q * 16 * o_stride);\
    }                                                                           \
  }

  // convert + swizzled LDS store into buffer b_: row = r0+16q; granule gh^(row&7)
#define STORE_TILE(b_)                                                          \
  {                                                                             \
    _Pragma("unroll")                                                           \
    for (int q = 0; q < 8; ++q) {                                               \
      const int row = r0 + 16 * q;                                              \
      const int off = row * 64 + ((gh ^ (row & 7)) << 3) + half4;               \
      *reinterpret_cast<ushort4v*>(&As[b_][off]) = pack4(aL[q]);                \
      *reinterpret_cast<ushort4v*>(&Bs[b_][off]) = pack4(wL[q]);                \
    }                                                                           \
  }

  LOAD_TILE(0);
  STORE_TILE(0);
  LOAD_TILE(1);
  __syncthreads();                      // buf0 ready; loads(1) in flight

  int cur = 0;
  for (int t = 0; t < 32; ++t) {
    // MFMA phase on buf[cur]; pack of next tile + prefetch overlap underneath.
#pragma unroll
    for (int ks = 0; ks < 2; ++ks) {
      bf16x8 af[4], bf_[4];
#pragma unroll
      for (int i2 = 0; i2 < 4; ++i2) {
        const int row = wm + 16 * i2 + lr;
        const int col = (((ks * 4 + lq) ^ (row & 7)) << 3);
        af[i2] = *reinterpret_cast<const bf16x8*>(&As[cur][row * 64 + col]);
      }
#pragma unroll
      for (int j = 0; j < 4; ++j) {
        const int row = wn + 16 * j + lr;
        const int col = (((ks * 4 + lq) ^ (row & 7)) << 3);
        bf_[j] = *reinterpret_cast<const bf16x8*>(&Bs[cur][row * 64 + col]);
      }
#pragma unroll
      for (int i2 = 0; i2 < 4; ++i2)
#pragma unroll
        for (int j = 0; j < 4; ++j)
          acc[i2][j] = __builtin_amdgcn_mfma_f32_16x16x32_bf16(af[i2], bf_[j], acc[i2][j], 0, 0, 0);
    }
    if (t < 31) {
      STORE_TILE(cur ^ 1);              // waits (vmcnt) on loads(t+1), writes other buf
      if (t < 30) LOAD_TILE(t + 2);     // keep one tile of loads in flight
    }
    __syncthreads();                    // single barrier per step
    cur ^= 1;
  }
#undef LOAD_TILE
#undef STORE_TILE

  // bf16 partial store (D layout: row = lq*4+r, col = lr); m-half picks row block
  unsigned short* base = part + (long)pslot * PART_ELEMS + (long)m * 128 * NBATCH;
#pragma unroll
  for (int i2 = 0; i2 < 4; ++i2) {
#pragma unroll
    for (int j = 0; j < 4; ++j) {
#pragma unroll
      for (int r = 0; r < 4; ++r) {
        int s = wm + 16 * i2 + lq * 4 + r;
        int o = wn + 16 * j + lr;
        base[s * NBATCH + o] = f2bf(acc[i2][j][r]);
      }
    }
  }
}

// Epilogue stage 1: reduce 424 bf16 partials -> 33 fp32 slot-sums.
// Old single epilogue was ~170us: 128 wgs, 424 scalar 2B loads/thread,
// latency-bound. Now: 33 slots x 4096 ushort8-columns = 528 blocks, 16B loads,
// fixed-unroll chunks of 8 for MLP. Expected ~10-15us (27.75MB read, 4.3MB write).
__global__ void reduce_part(const unsigned short* __restrict__ part,
                            float* __restrict__ sums)
{
  const int t = blockIdx.x * 256 + threadIdx.x;   // 33 * 4096 threads
  const int sl   = t >> 12;                        // slot 0..32 (wave-uniform)
  const int col8 = t & 4095;                       // ushort8 column

  int cb, cc;
  if (sl < 18)      { cb = sl * 8;             cc = 8;  }
  else if (sl < 28) { cb = 144 + (sl - 18) * 16; cc = 16; }
  else              { cb = 304 + (sl - 28) * 24; cc = 24; }

  const unsigned short* p0 = part + (long)cb * PART_ELEMS + (long)col8 * 8;

  float acc[8];
#pragma unroll
  for (int j = 0; j < 8; ++j) acc[j] = 0.f;

#define ADD8(c_)                                                        \
  {                                                                     \
    ushort8v v = *reinterpret_cast<const ushort8v*>(p0 + (long)(c_) * PART_ELEMS); \
    _Pragma("unroll")                                                   \
    for (int j = 0; j < 8; ++j) acc[j] += bf2f(v[j]);                   \
  }

#pragma unroll
  for (int c = 0; c < 8; ++c) ADD8(c);
  if (cc > 8) {
#pragma unroll
    for (int c = 8; c < 16; ++c) ADD8(c);
  }
  if (cc > 16) {
#pragma unroll
    for (int c = 16; c < 24; ++c) ADD8(c);
  }
#undef ADD8

  float* sp = sums + (long)sl * PART_ELEMS + (long)col8 * 8;
  reinterpret_cast<float4*>(sp)[0] = make_float4(acc[0], acc[1], acc[2], acc[3]);
  reinterpret_cast<float4*>(sp)[1] = make_float4(acc[4], acc[5], acc[6], acc[7]);
}

// Epilogue stage 2: maxpool over slots + bias + ReLU + transpose-store.
__global__ void finalize(const float* __restrict__ sums,
                         const float* __restrict__ b1, const float* __restrict__ b2,
                         const float* __restrict__ b3, float* __restrict__ out)
{
  const int t = blockIdx.x * 256 + threadIdx.x;   // 32768 threads: (s,o)
  const int o = t & 127;
  const int s = t >> 7;

  float v[33];
#pragma unroll
  for (int sl = 0; sl < 33; ++sl) v[sl] = sums[(long)sl * PART_ELEMS + t];

  float r[16];
#pragma unroll
  for (int k = 0; k < 6; ++k) {   // h=1, kernels 3k
    float mx = fmaxf(fmaxf(v[3 * k + 0], v[3 * k + 1]), v[3 * k + 2]);
    r[3 * k + 0] = fmaxf(mx + b1[k * 128 + o], 0.f);
  }
#pragma unroll
  for (int k = 0; k < 5; ++k) {   // h=2, kernels 3k+1
    float mx = fmaxf(v[18 + 2 * k], v[18 + 2 * k + 1]);
    r[3 * k + 1] = fmaxf(mx + b2[k * 128 + o], 0.f);
  }
#pragma unroll
  for (int k = 0; k < 5; ++k) {   // h=3, kernels 3k+2
    r[3 * k + 2] = fmaxf(v[28 + k] + b3[k * 128 + o], 0.f);
  }
  float* op = out + ((long)o * 256 + s) * 16;   // out[B][S][1][K]
  reinterpret_cast<float4*>(op)[0] = make_float4(r[0], r[1], r[2], r[3]);
  reinterpret_cast<float4*>(op)[1] = make_float4(r[4], r[5], r[6], r[7]);
  reinterpret_cast<float4*>(op)[2] = make_float4(r[8], r[9], r[10], r[11]);
  reinterpret_cast<float4*>(op)[3] = make_float4(r[12], r[13], r[14], r[15]);
}

extern "C" void kernel_launch(void* const* d_in, const int* in_sizes, int n_in,
                              void* d_out, int out_size, void* d_ws, size_t ws_size,
                              hipStream_t stream) {
  const float* Ec = (const float*)d_in[0];
  const float* W1 = (const float*)d_in[1];
  const float* W2 = (const float*)d_in[2];
  const float* W3 = (const float*)d_in[3];
  const float* b1 = (const float*)d_in[4];
  const float* b2 = (const float*)d_in[5];
  const float* b3 = (const float*)d_in[6];
  float* out = (float*)d_out;
  unsigned short* part = (unsigned short*)d_ws;            // 27.79 MB bf16
  float* sums = (float*)((unsigned short*)d_ws + SUMS_OFF_SHORTS);  // 4.33 MB fp32

  gemm_uniform<<<848, 256, 0, stream>>>(Ec, W1, W2, W3, part);
  reduce_part<<<(33 * 4096) / 256, 256, 0, stream>>>(part, sums);
  finalize<<<(NSLIDE * NBATCH) / 256, 256, 0, stream>>>(sums, b1, b2, b3, out);
}